// Round 23
// baseline (198.734 us; speedup 1.0000x reference)
//
#include <hip/hip_runtime.h>

#define T_STEPS 512
#define HID 128
#define ROWS 16   // rows per sequence
#define SEQS 2    // sequences per block, wave-split -> 32 blocks
#define SCALE 2.885390081777926816f   // 2*log2(e)

typedef short bf16x8 __attribute__((ext_vector_type(8)));   // MFMA A/B frag
typedef float f32x4  __attribute__((ext_vector_type(4)));   // MFMA C/D frag
typedef unsigned int u32;
typedef u32 u32x4 __attribute__((ext_vector_type(4)));

// R22 lean body (134.7us, 5-MFMA chain, xw table, exp2 tanh) + cross-wave
// 2-seq stagger: 1024 thr = 16 waves = 4/SIMD; waves 0-7 seqA, 8-15 seqB.
// R17 measured +20% per-step-equiv from this stagger at the fat body (747 vs
// 933); this is the same cell on the lean body. W/Ap frags shared between
// seqs; h buffers and xw tables per-seq.

// LDS map:
//   0       h[s][parity]: s*8192 + parity*4096 (slot-major, R16-verified)
//   16384   xw table seq s: +s*65536, [t][r] uint2 (64KB each)
//   147456  zero pad (8B)
//   147472  red [2 s][8 wv][16 r] f32 (1KB)
#define HB(S)    ((S) * 8192)
#define XW(S)    (16384 + (S) * 65536)
#define Z_OFF    147456
#define RED_OFF  147472
#define LDS_BYTES (147472 + 1024)

__device__ __forceinline__ u32 cvt_pk_bf16(float s0, float s1) {
    u32 d;  // d.lo = bf16(s0), d.hi = bf16(s1)
    asm("v_cvt_pk_bf16_f32 %0, %1, %2" : "=v"(d) : "v"(s0), "v"(s1));
    return d;
}
__device__ __forceinline__ bf16x8 frag_from(u32 a, u32 b, u32 c, u32 d) {
    u32x4 t = {a, b, c, d};
    return __builtin_bit_cast(bf16x8, t);
}

#define MFMA(ACC, A, B) \
    ACC = __builtin_amdgcn_mfma_f32_16x16x32_bf16(A, B, ACC, 0, 0, 0);

__global__ __launch_bounds__(1024)
__attribute__((amdgpu_waves_per_eu(4, 4)))
void rnn_lean_x2_kernel(const float* __restrict__ x,
                        const float* __restrict__ W_ih,
                        const float* __restrict__ W_hh,
                        const float* __restrict__ b_ih,
                        const float* __restrict__ b_hh,
                        const float* __restrict__ W_out,
                        const float* __restrict__ b_out,
                        float* __restrict__ y)
{
    __shared__ __align__(16) char lds[LDS_BYTES];

    const int tid = threadIdx.x;
    const int w   = tid >> 6;        // wave 0..15
    const int s   = w >> 3;          // sequence 0/1
    const int wv  = w & 7;           // j-tile [16wv, 16wv+16) within seq
    const int l   = tid & 63;
    const int q   = l >> 4;          // lane quarter (k-group / C row group)
    const int r   = l & 15;          // batch row within seq
    const int b0  = blockIdx.x * (SEQS * ROWS);

    // ---- zero both seqs' h buf0 (1024 threads x 8 B = 8 KB)
    *(uint2*)&lds[(tid >> 9) * 8192 + (tid & 511) * 8] = make_uint2(0u, 0u);
    if (tid == 0) *(uint2*)&lds[Z_OFF] = make_uint2(0u, 0u);

    // ---- pre-pass: xw[s][t][r] = {bw0, bw1} (2 x 64 KB)
    for (int i = tid; i < SEQS * ROWS * T_STEPS; i += 1024) {
        const int s_  = i >> 13;
        const int rem = i & 8191;
        const int rr  = rem >> 9;        // consecutive tid -> consecutive t
        const int tt  = rem & 511;
        const float xv = x[(size_t)(b0 + s_ * ROWS + rr) * T_STEPS + tt];
        const u32 w0 = cvt_pk_bf16(1.0f, xv);
        const float xh = __uint_as_float(w0 & 0xffff0000u);
        const u32 w1 = cvt_pk_bf16(xh, xv - xh);
        *(uint2*)&lds[XW(s_) + (tt * 16 + rr) * 8] = make_uint2(w0, w1);
    }

    // ---- W_hh A-frags, plain bf16, PRE-SCALED (shared by both seqs)
    bf16x8 WH0, WH1, WH2, WH3;
    {
        const float* p = W_hh + (size_t)(16 * wv + r) * HID + 8 * q;
#define LDW(DST, OFF) do {                                                    \
    float4 fa_ = *(const float4*)(p + (OFF));                                 \
    float4 fb_ = *(const float4*)(p + (OFF) + 4);                             \
    DST = frag_from(cvt_pk_bf16(fa_.x*SCALE, fa_.y*SCALE),                    \
                    cvt_pk_bf16(fa_.z*SCALE, fa_.w*SCALE),                    \
                    cvt_pk_bf16(fb_.x*SCALE, fb_.y*SCALE),                    \
                    cvt_pk_bf16(fb_.z*SCALE, fb_.w*SCALE));                   \
} while (0)
        LDW(WH0,  0); LDW(WH1, 32); LDW(WH2, 64); LDW(WH3, 96);
#undef LDW
    }

    // ---- bias/x MFMA A'-frag (scaled; only q==0 lanes nonzero)
    bf16x8 Ap;
    {
        const int jA = 16 * wv + r;
        const float bias = (b_ih[jA] + b_hh[jA]) * SCALE;
        const float wih  = W_ih[jA] * SCALE;
        const float bm   = (q == 0) ? bias : 0.0f;
        const float wm   = (q == 0) ? wih  : 0.0f;
        const u32 w0 = cvt_pk_bf16(bm, wm);                       // e0,e1
        const float wl = wm - __uint_as_float(w0 & 0xffff0000u);
        const float bl = bm - __uint_as_float(w0 << 16);
        const u32 w1 = cvt_pk_bf16(wl, wm);                       // e2,e3
        const u32 w2 = cvt_pk_bf16(bl, 0.0f);                     // e4,e5
        Ap = frag_from(w0, w1, w2, 0u);
    }
    const u32 bpw2 = cvt_pk_bf16((q == 0) ? 1.0f : 0.0f, 0.0f);   // B' word2

    const int j0 = 16 * wv + 4 * q;

    // ---- slot-major LDS offsets (R16-verified), relative to HB(s)+parity
    const int rswz  = ((r >> 3) << 4) ^ ((q & 1) << 5);
    const int roff0 = ((l * 16) ^ rswz);
    const int cw    = j0 >> 5;
    const int qw    = (j0 >> 3) & 3;
    const int woff  = cw * 1024 +
        ((((qw * 16 + r) * 16) + (j0 & 7) * 2) ^ ((r >> 3) << 4) ^ ((qw & 1) << 5));

    // ---- xw stream pointer: q==0 lanes walk the table, others read zeros
    u32 xaddr         = (q == 0) ? (u32)(XW(s) + r * 8) : (u32)Z_OFF;
    const u32 xstride = (q == 0) ? 128u : 0u;

    const u32 hb = (u32)HB(s);
    f32x4 hv;
    __syncthreads();

#define STEP(RB, WB) do {                                                     \
    const bf16x8 B0 = *(const bf16x8*)&lds[hb + (RB) + roff0];                \
    const bf16x8 B1 = *(const bf16x8*)&lds[hb + (RB) + roff0 + 1024];         \
    const bf16x8 B2 = *(const bf16x8*)&lds[hb + (RB) + roff0 + 2048];         \
    const bf16x8 B3 = *(const bf16x8*)&lds[hb + (RB) + roff0 + 3072];         \
    const uint2 bw  = *(const uint2*)&lds[xaddr];                             \
    const bf16x8 Bp = frag_from(bw.x, bw.y, bpw2, 0u);                        \
    f32x4 acc = __builtin_amdgcn_mfma_f32_16x16x32_bf16(                      \
        Ap, Bp, (f32x4)(0.0f), 0, 0, 0);                                      \
    MFMA(acc, WH0, B0) MFMA(acc, WH1, B1)                                     \
    MFMA(acc, WH2, B2) MFMA(acc, WH3, B3)                                     \
    const float e0 = __builtin_amdgcn_exp2f(acc[0]);                          \
    const float e1 = __builtin_amdgcn_exp2f(acc[1]);                          \
    const float e2 = __builtin_amdgcn_exp2f(acc[2]);                          \
    const float e3 = __builtin_amdgcn_exp2f(acc[3]);                          \
    const float rc0 = __builtin_amdgcn_rcpf(e0 + 1.0f);                       \
    const float rc1 = __builtin_amdgcn_rcpf(e1 + 1.0f);                       \
    const float rc2 = __builtin_amdgcn_rcpf(e2 + 1.0f);                       \
    const float rc3 = __builtin_amdgcn_rcpf(e3 + 1.0f);                       \
    hv[0] = fmaf(-2.0f, rc0, 1.0f); hv[1] = fmaf(-2.0f, rc1, 1.0f);           \
    hv[2] = fmaf(-2.0f, rc2, 1.0f); hv[3] = fmaf(-2.0f, rc3, 1.0f);           \
    *(uint2*)&lds[hb + (WB) + woff] =                                         \
        make_uint2(cvt_pk_bf16(hv[0], hv[1]), cvt_pk_bf16(hv[2], hv[3]));     \
    xaddr += xstride;                                                         \
    __syncthreads();                                                          \
} while (0)

    for (int t = 0; t < T_STEPS; t += 2) {
        STEP(0,    4096);
        STEP(4096, 0);
    }
#undef STEP

    // ---- y = h_last . W_out + b_out (per seq)
    const float4 wo = *(const float4*)(W_out + j0);
    float v = wo.x*hv[0] + wo.y*hv[1] + wo.z*hv[2] + wo.w*hv[3];
    v += __shfl_xor(v, 16, 64);
    v += __shfl_xor(v, 32, 64);          // lane r: sum over this tile's 16 j
    if (l < 16) *(float*)&lds[RED_OFF + s * 512 + (wv * 16 + r) * 4] = v;
    __syncthreads();
    if (tid < 32) {
        const int ss = tid >> 4, rr = tid & 15;
        float acc = 0.0f;
        #pragma unroll
        for (int ww = 0; ww < 8; ++ww)
            acc += *(const float*)&lds[RED_OFF + ss * 512 + (ww * 16 + rr) * 4];
        y[b0 + ss * ROWS + rr] = acc + b_out[0];
    }
}

extern "C" void kernel_launch(void* const* d_in, const int* in_sizes, int n_in,
                              void* d_out, int out_size, void* d_ws, size_t ws_size,
                              hipStream_t stream)
{
    const float* x     = (const float*)d_in[0];
    const float* W_ih  = (const float*)d_in[1];
    const float* W_hh  = (const float*)d_in[2];
    const float* b_ih  = (const float*)d_in[3];
    const float* b_hh  = (const float*)d_in[4];
    const float* W_out = (const float*)d_in[5];
    const float* b_out = (const float*)d_in[6];
    float* y = (float*)d_out;

    const int B = in_sizes[0] / T_STEPS;   // 1024
    rnn_lean_x2_kernel<<<B / (SEQS * ROWS), 1024, 0, stream>>>(
        x, W_ih, W_hh, b_ih, b_hh, W_out, b_out, y);
}

// Round 24
// 135.281 us; speedup vs baseline: 1.4690x; 1.4690x over previous
//
#include <hip/hip_runtime.h>

#define T_STEPS 512
#define HID 128
#define ROWS 16   // batch rows per block -> 64 blocks
#define SCALE 2.885390081777926816f   // 2*log2(e)

typedef short bf16x8 __attribute__((ext_vector_type(8)));   // MFMA A/B frag
typedef float f32x4  __attribute__((ext_vector_type(4)));   // MFMA C/D frag
typedef unsigned int u32;
typedef u32 u32x4 __attribute__((ext_vector_type(4)));

// R22 (134.7us) + ONE change: bias-MFMA removed. 4-MFMA chain computes
// W_hh*h only; x*W_ih + bias (pre-scaled) is applied as a f32 post-add on
// the D output before tanh: bxt_i = fmaf(xt, wihs_i, biass_i) is computable
// DURING the MFMA chain (independent), only the 4 adds land on the critical
// path. Kills the B' fragment machinery + 1 serial MFMA (~34-40cyc, R11-law);
// xw uint2 table replaced by plain f32 xs table (32 KB). Bias now in f32
// (slightly better numerics than the bf16 A'/B' trick).

// LDS map: 0 h buf0 | 4096 h buf1 (slot-major, R16-verified)
//          8192 xs table [t][r] f32 (32KB) | 40960 red
#define XS_OFF   8192
#define RED_OFF  40960
#define LDS_BYTES (40960 + 512)

__device__ __forceinline__ u32 cvt_pk_bf16(float s0, float s1) {
    u32 d;  // d.lo = bf16(s0), d.hi = bf16(s1)
    asm("v_cvt_pk_bf16_f32 %0, %1, %2" : "=v"(d) : "v"(s0), "v"(s1));
    return d;
}
__device__ __forceinline__ bf16x8 frag_from(u32 a, u32 b, u32 c, u32 d) {
    u32x4 t = {a, b, c, d};
    return __builtin_bit_cast(bf16x8, t);
}

#define MFMA(ACC, A, B) \
    ACC = __builtin_amdgcn_mfma_f32_16x16x32_bf16(A, B, ACC, 0, 0, 0);

__global__ __launch_bounds__(512, 1)
__attribute__((amdgpu_waves_per_eu(2, 2)))
void rnn_lean4_kernel(const float* __restrict__ x,
                      const float* __restrict__ W_ih,
                      const float* __restrict__ W_hh,
                      const float* __restrict__ b_ih,
                      const float* __restrict__ b_hh,
                      const float* __restrict__ W_out,
                      const float* __restrict__ b_out,
                      float* __restrict__ y)
{
    __shared__ __align__(16) char lds[LDS_BYTES];

    const int tid = threadIdx.x;
    const int w   = tid >> 6;        // wave 0..7: j-tile [16w, 16w+16)
    const int l   = tid & 63;
    const int q   = l >> 4;          // lane quarter (k-group / C row group)
    const int r   = l & 15;          // batch row (A row m / B col n / C col n)
    const int b0  = blockIdx.x * ROWS;

    // ---- zero h buf0 (4 KB)
    *(uint2*)&lds[tid * 8] = make_uint2(0u, 0u);

    // ---- pre-pass: xs[t][r] = x[b0+r][t] (32 KB, coalesced)
    for (int i = tid; i < ROWS * T_STEPS; i += 512) {
        const int rr = i >> 9;           // consecutive tid -> consecutive t
        const int tt = i & 511;
        *(float*)&lds[XS_OFF + (tt * 16 + rr) * 4] =
            x[(size_t)(b0 + rr) * T_STEPS + tt];
    }

    // ---- W_hh A-frags, plain bf16, PRE-SCALED by 2log2e: lane(q,r) k=8q+e+32c
    bf16x8 WH0, WH1, WH2, WH3;
    {
        const float* p = W_hh + (size_t)(16 * w + r) * HID + 8 * q;
#define LDW(DST, OFF) do {                                                    \
    float4 fa_ = *(const float4*)(p + (OFF));                                 \
    float4 fb_ = *(const float4*)(p + (OFF) + 4);                             \
    DST = frag_from(cvt_pk_bf16(fa_.x*SCALE, fa_.y*SCALE),                    \
                    cvt_pk_bf16(fa_.z*SCALE, fa_.w*SCALE),                    \
                    cvt_pk_bf16(fb_.x*SCALE, fb_.y*SCALE),                    \
                    cvt_pk_bf16(fb_.z*SCALE, fb_.w*SCALE));                   \
} while (0)
        LDW(WH0,  0); LDW(WH1, 32); LDW(WH2, 64); LDW(WH3, 96);
#undef LDW
    }

    // ---- per-lane f32 epilogue constants: wih/bias (scaled) for j0..j0+3
    const int j0 = 16 * w + 4 * q;
    float4 wihs, biass;
    {
        const float4 wi = *(const float4*)(W_ih + j0);
        const float4 bi = *(const float4*)(b_ih + j0);
        const float4 bh = *(const float4*)(b_hh + j0);
        wihs.x  = wi.x * SCALE;  wihs.y  = wi.y * SCALE;
        wihs.z  = wi.z * SCALE;  wihs.w  = wi.w * SCALE;
        biass.x = (bi.x + bh.x) * SCALE; biass.y = (bi.y + bh.y) * SCALE;
        biass.z = (bi.z + bh.z) * SCALE; biass.w = (bi.w + bh.w) * SCALE;
    }

    // ---- slot-major LDS offsets (R16-verified)
    const int rswz  = ((r >> 3) << 4) ^ ((q & 1) << 5);
    const int roff0 = ((l * 16) ^ rswz);
    const int cw    = j0 >> 5;
    const int qw    = (j0 >> 3) & 3;
    const int woff  = cw * 1024 +
        ((((qw * 16 + r) * 16) + (j0 & 7) * 2) ^ ((r >> 3) << 4) ^ ((qw & 1) << 5));

    // ---- xs stream pointer (lane reads its column r; 16 consecutive words,
    // broadcast across quarters -> conflict-free)
    u32 xaddr = (u32)(XS_OFF + r * 4);

    f32x4 hv;
    __syncthreads();

#define STEP(RB, WB) do {                                                     \
    const bf16x8 B0 = *(const bf16x8*)&lds[(RB) + roff0];                     \
    const bf16x8 B1 = *(const bf16x8*)&lds[(RB) + roff0 + 1024];              \
    const bf16x8 B2 = *(const bf16x8*)&lds[(RB) + roff0 + 2048];              \
    const bf16x8 B3 = *(const bf16x8*)&lds[(RB) + roff0 + 3072];              \
    const float xt = *(const float*)&lds[xaddr];                              \
    /* bxt computable during the MFMA chain (independent of acc) */           \
    const float bxt0 = fmaf(xt, wihs.x, biass.x);                             \
    const float bxt1 = fmaf(xt, wihs.y, biass.y);                             \
    const float bxt2 = fmaf(xt, wihs.z, biass.z);                             \
    const float bxt3 = fmaf(xt, wihs.w, biass.w);                             \
    f32x4 acc = __builtin_amdgcn_mfma_f32_16x16x32_bf16(                      \
        WH0, B0, (f32x4)(0.0f), 0, 0, 0);                                     \
    MFMA(acc, WH1, B1) MFMA(acc, WH2, B2) MFMA(acc, WH3, B3)                  \
    const float e0 = __builtin_amdgcn_exp2f(acc[0] + bxt0);                   \
    const float e1 = __builtin_amdgcn_exp2f(acc[1] + bxt1);                   \
    const float e2 = __builtin_amdgcn_exp2f(acc[2] + bxt2);                   \
    const float e3 = __builtin_amdgcn_exp2f(acc[3] + bxt3);                   \
    const float rc0 = __builtin_amdgcn_rcpf(e0 + 1.0f);                       \
    const float rc1 = __builtin_amdgcn_rcpf(e1 + 1.0f);                       \
    const float rc2 = __builtin_amdgcn_rcpf(e2 + 1.0f);                       \
    const float rc3 = __builtin_amdgcn_rcpf(e3 + 1.0f);                       \
    hv[0] = fmaf(-2.0f, rc0, 1.0f); hv[1] = fmaf(-2.0f, rc1, 1.0f);           \
    hv[2] = fmaf(-2.0f, rc2, 1.0f); hv[3] = fmaf(-2.0f, rc3, 1.0f);           \
    *(uint2*)&lds[(WB) + woff] =                                              \
        make_uint2(cvt_pk_bf16(hv[0], hv[1]), cvt_pk_bf16(hv[2], hv[3]));     \
    xaddr += 64u;                                                             \
    __syncthreads();                                                          \
} while (0)

    for (int t = 0; t < T_STEPS; t += 2) {
        STEP(0,    4096);
        STEP(4096, 0);
    }
#undef STEP

    // ---- y[b0+r] = sum_j W_out[j] * h_last[j] + b_out
    const float4 wo = *(const float4*)(W_out + j0);
    float v = wo.x*hv[0] + wo.y*hv[1] + wo.z*hv[2] + wo.w*hv[3];
    v += __shfl_xor(v, 16, 64);
    v += __shfl_xor(v, 32, 64);          // lane r: sum over this tile's 16 j
    if (l < 16) *(float*)&lds[RED_OFF + (w * 16 + r) * 4] = v;
    __syncthreads();
    if (tid < 16) {
        float s = 0.0f;
        #pragma unroll
        for (int ww = 0; ww < 8; ++ww)
            s += *(const float*)&lds[RED_OFF + (ww * 16 + tid) * 4];
        y[b0 + tid] = s + b_out[0];
    }
}

extern "C" void kernel_launch(void* const* d_in, const int* in_sizes, int n_in,
                              void* d_out, int out_size, void* d_ws, size_t ws_size,
                              hipStream_t stream)
{
    const float* x     = (const float*)d_in[0];
    const float* W_ih  = (const float*)d_in[1];
    const float* W_hh  = (const float*)d_in[2];
    const float* b_ih  = (const float*)d_in[3];
    const float* b_hh  = (const float*)d_in[4];
    const float* W_out = (const float*)d_in[5];
    const float* b_out = (const float*)d_in[6];
    float* y = (float*)d_out;

    const int B = in_sizes[0] / T_STEPS;   // 1024
    rnn_lean4_kernel<<<B / ROWS, 512, 0, stream>>>(x, W_ih, W_hh, b_ih, b_hh,
                                                   W_out, b_out, y);
}